// Round 11
// baseline (43.061 us; speedup 1.0000x reference)
//
#include <hip/hip_runtime.h>
#include <hip/hip_bf16.h>
#include <cstdint>

// LearnableUpsamplingLayer: polyphase decomposition + bf16 MFMA.
// B=8, T=16384, C=64, F=64, filter=5, leaky 0.3.
// out[b,2t+p,f] = sum_tap M_p[tap][c,f] * x[t-1+tap, c]   (x outside [0,T) = 0)
// Even p=0: 3 taps; odd p=1: 4 taps. Frames 0,1 get a precomputed correction
// (the polyphase substitution leaks a (1-w)*x[0] term through blend[-1]).
//
// R11: occupancy attack. Invariant of all ~32us variants was the 56-VGPR
// resident weight table -> >64 VGPR -> 16 waves/CU cap (m69) -> too little
// MLP to stream HBM. Now: weights are TRANSIENT per-tap b128 loads from L2
// (bp = 57 KB, L2-resident after first generation; opaque-pointer asm stops
// LICM from rebuilding the resident table), staging is the proven R1
// block-cooperative bf16 path (9.7 KB LDS, fragments = direct ds_read_b128),
// one __syncthreads, __launch_bounds__(256,8) forcing <=64 VGPR ->
// 8 blocks/CU, 32 waves/CU. Operand-swapped MFMA (W=A) -> dwordx4 stores.

#define T_ 16384
#define TWO_T 32768
#define NFR 67             // staged frames: p0-1 .. p0+65
#define XSTRIDE 72         // ushorts per frame row (144 B; <=2-way banks)

typedef __bf16 bf16x8 __attribute__((ext_vector_type(8)));
typedef __bf16 bf16x4 __attribute__((ext_vector_type(4)));
typedef float  f32x4  __attribute__((ext_vector_type(4)));
typedef unsigned short u16x8 __attribute__((ext_vector_type(8)));

__device__ __forceinline__ float sigmoidf_(float z) {
    return 1.0f / (1.0f + expf(-z));
}

__device__ __forceinline__ unsigned short f2bf(float f) {
    union { float f; uint32_t u; } v; v.f = f;
    uint32_t u = v.u;
    return (unsigned short)((u + 0x7FFFu + ((u >> 16) & 1u)) >> 16);
}

// ---------------- prep: 64 blocks x 64 threads (proven, unchanged).
// Blocks 0..55: the 7 polyphase matrices as packed bf16 fragments:
//   frag (phase, ks, nt): lane l elem i = M[tap=ks>>1][c=(ks&1)*32+(l>>4)*8+i]
//                                          [f=nt*16+(l&15)]
// Blocks 56..63: b = fi-56; corr[b][{E,O}][f] = sum_c K[{1,0}][c][f]*(1-w_c)*x[b,0,c]
__global__ void lu_prep_kernel(const float* __restrict__ iw,
                               const float* __restrict__ ck,
                               const float* __restrict__ x,
                               unsigned short* __restrict__ bp,
                               float* __restrict__ corrf) {
    int fi = blockIdx.x;
    int l  = threadIdx.x;
    if (fi < 56) {
        int phase, ks, nt;
        if (fi < 24) { phase = 0; ks = fi >> 2; nt = fi & 3; }
        else         { phase = 1; ks = (fi - 24) >> 2; nt = (fi - 24) & 3; }
        int tap = ks >> 1;
        int n   = nt * 16 + (l & 15);
        int c0  = ((ks & 1) << 5) + ((l >> 4) << 3);
        u16x8 pk;
#pragma unroll
        for (int i = 0; i < 8; ++i) {
            int c = c0 + i;
            float w = sigmoidf_(iw[c]);
            float v;
            #define CK(k) ck[((k) * 64 + c) * 64 + n]
            if (phase == 0) {
                if (tap == 0)      v = CK(0) + w * CK(1);
                else if (tap == 1) v = (1.f - w) * CK(1) + CK(2) + w * CK(3);
                else               v = (1.f - w) * CK(3) + CK(4);
            } else {
                if (tap == 0)      v = w * CK(0);
                else if (tap == 1) v = (1.f - w) * CK(0) + CK(1) + w * CK(2);
                else if (tap == 2) v = (1.f - w) * CK(2) + CK(3) + w * CK(4);
                else               v = (1.f - w) * CK(4);
            }
            #undef CK
            pk[i] = f2bf(v);
        }
        *(u16x8*)(bp + (((size_t)fi * 64) + l) * 8) = pk;
    } else {
        int b = fi - 56;
        int f = l;
        float cE = 0.f, cO = 0.f;
#pragma unroll
        for (int c = 0; c < 64; ++c) {
            float w = sigmoidf_(iw[c]);
            float g = (1.f - w) * x[(size_t)b * T_ * 64 + c];
            cE += ck[(64 + c) * 64 + f] * g;   // K1
            cO += ck[c * 64 + f] * g;          // K0
        }
        corrf[b * 128 + f]      = cE;
        corrf[b * 128 + 64 + f] = cO;
    }
}

// ---------------- main ----------------
__global__ __launch_bounds__(256, 8) void lu_main_kernel(
        const float* __restrict__ x,
        const unsigned short* __restrict__ bp,
        const float* __restrict__ corrf,
        const float* __restrict__ bias,
        float* __restrict__ out) {
    __shared__ __align__(16) unsigned short xl[NFR * XSTRIDE];   // 9,648 B

    const int bid  = blockIdx.x;        // 0..2047
    const int b    = bid >> 8;
    const int q    = bid & 255;
    const int p0   = q << 6;            // 64 time-pairs per block
    const int tid  = threadIdx.x;
    const int lane = tid & 63;
    const int wv   = tid >> 6;          // wave = filter tile

    const float* xb = x + (size_t)b * T_ * 64;

    // ---- cooperative staging: 67 frames x 16 chunks = 1072 items ----
#pragma unroll
    for (int it = 0; it < 5; ++it) {
        int idx = it * 256 + tid;
        if (idx < NFR * 16) {
            int j  = idx >> 4;
            int c4 = (idx & 15) << 2;
            int gf = p0 - 1 + j;
            float4 v = make_float4(0.f, 0.f, 0.f, 0.f);
            if ((unsigned)gf < (unsigned)T_)
                v = *(const float4*)(xb + ((size_t)gf << 6) + c4);
            bf16x4 pk;
            pk[0] = (__bf16)v.x; pk[1] = (__bf16)v.y;
            pk[2] = (__bf16)v.z; pk[3] = (__bf16)v.w;
            *(bf16x4*)(xl + j * XSTRIDE + c4) = pk;
        }
    }

    const int hi  = lane >> 4;
    const int col = lane & 15;          // time-pair within window
    const float4 bias4 = *(const float4*)(bias + (wv << 4) + (hi << 2));

    __syncthreads();

#pragma unroll 1
    for (int w = 0; w < 4; ++w) {
        // opaque base per iteration: stops LICM from hoisting the 14 weight
        // loads into a resident 56-VGPR table (the occupancy killer)
        uint64_t bpa = (uint64_t)bp;
        asm("" : "+v"(bpa));
        const unsigned short* bpw = (const unsigned short*)bpa;

        f32x4 accE = {0.f, 0.f, 0.f, 0.f};
        f32x4 accO = {0.f, 0.f, 0.f, 0.f};
#pragma unroll
        for (int tap = 0; tap < 4; ++tap) {
            int r = (w << 4) + col + tap;               // row 0..66
            bf16x8 x0 = __builtin_bit_cast(bf16x8,
                *(const u16x8*)(xl + r * XSTRIDE + (hi << 3)));
            bf16x8 x1 = __builtin_bit_cast(bf16x8,
                *(const u16x8*)(xl + r * XSTRIDE + 32 + (hi << 3)));
            // weight fragments for ks = 2*tap, 2*tap+1 (transient, from L2)
            const size_t f0 = (size_t)(((tap * 2) * 4 + wv) * 64 + lane) * 8;
            const size_t f1 = (size_t)(((tap * 2 + 1) * 4 + wv) * 64 + lane) * 8;
            if (tap < 3) {
                bf16x8 we0 = __builtin_bit_cast(bf16x8, *(const u16x8*)(bpw + f0));
                bf16x8 we1 = __builtin_bit_cast(bf16x8, *(const u16x8*)(bpw + f1));
                accE = __builtin_amdgcn_mfma_f32_16x16x32_bf16(we0, x0, accE, 0, 0, 0);
                accE = __builtin_amdgcn_mfma_f32_16x16x32_bf16(we1, x1, accE, 0, 0, 0);
            }
            bf16x8 wo0 = __builtin_bit_cast(bf16x8, *(const u16x8*)(bpw + f0 + 12288));
            bf16x8 wo1 = __builtin_bit_cast(bf16x8, *(const u16x8*)(bpw + f1 + 12288));
            accO = __builtin_amdgcn_mfma_f32_16x16x32_bf16(wo0, x0, accO, 0, 0, 0);
            accO = __builtin_amdgcn_mfma_f32_16x16x32_bf16(wo1, x1, accO, 0, 0, 0);
        }

        // ---- boundary correction (output frames 0,1 of each batch) ----
        if (((q | w) == 0) && col == 0) {
            const float4 cE4 = *(const float4*)(corrf + b * 128 + (wv << 4) + (hi << 2));
            const float4 cO4 = *(const float4*)(corrf + b * 128 + 64 + (wv << 4) + (hi << 2));
            accE[0] -= cE4.x; accE[1] -= cE4.y; accE[2] -= cE4.z; accE[3] -= cE4.w;
            accO[0] -= cO4.x; accO[1] -= cO4.y; accO[2] -= cO4.z; accO[3] -= cO4.w;
        }

        // ---- epilogue: bias + leaky_relu, one dwordx4 store per phase ----
        const int tl = p0 + (w << 4) + col;
        const size_t fbase = ((size_t)b * TWO_T + ((size_t)tl << 1)) * 64
                           + (wv << 4) + (hi << 2);
        float4 vE, vO;
        {
            float e0 = accE[0] + bias4.x, e1 = accE[1] + bias4.y,
                  e2 = accE[2] + bias4.z, e3 = accE[3] + bias4.w;
            vE.x = e0 >= 0.f ? e0 : 0.3f * e0;
            vE.y = e1 >= 0.f ? e1 : 0.3f * e1;
            vE.z = e2 >= 0.f ? e2 : 0.3f * e2;
            vE.w = e3 >= 0.f ? e3 : 0.3f * e3;
            float o0 = accO[0] + bias4.x, o1 = accO[1] + bias4.y,
                  o2 = accO[2] + bias4.z, o3 = accO[3] + bias4.w;
            vO.x = o0 >= 0.f ? o0 : 0.3f * o0;
            vO.y = o1 >= 0.f ? o1 : 0.3f * o1;
            vO.z = o2 >= 0.f ? o2 : 0.3f * o2;
            vO.w = o3 >= 0.f ? o3 : 0.3f * o3;
        }
        *(float4*)(out + fbase)      = vE;   // even frame 2*tl
        *(float4*)(out + fbase + 64) = vO;   // odd frame 2*tl+1
    }
}

extern "C" void kernel_launch(void* const* d_in, const int* in_sizes, int n_in,
                              void* d_out, int out_size, void* d_ws, size_t ws_size,
                              hipStream_t stream) {
    (void)in_sizes; (void)n_in; (void)out_size; (void)ws_size;
    const float* x    = (const float*)d_in[0];
    const float* iw   = (const float*)d_in[1];
    const float* ck   = (const float*)d_in[2];
    const float* bias = (const float*)d_in[3];
    float* out = (float*)d_out;
    unsigned short* bp = (unsigned short*)d_ws;            // 57,344 B
    float* corrf = (float*)((char*)d_ws + 57344);          // 4,096 B

    lu_prep_kernel<<<64, 64, 0, stream>>>(iw, ck, x, bp, corrf);
    lu_main_kernel<<<2048, 256, 0, stream>>>(x, bp, corrf, bias, out);
}

// Round 14
// 34.478 us; speedup vs baseline: 1.2490x; 1.2490x over previous
//
#include <hip/hip_runtime.h>
#include <hip/hip_bf16.h>
#include <cstdint>

// LearnableUpsamplingLayer: polyphase decomposition + bf16 MFMA.
// B=8, T=16384, C=64, F=64, filter=5, leaky 0.3.
// out[b,2t+p,f] = sum_tap M_p[tap][c,f] * x[t-1+tap, c]   (x outside [0,T) = 0)
// Even p=0: 3 taps; odd p=1: 4 taps. Frames 0,1 get a precomputed correction
// (the polyphase substitution leaks a (1-w)*x[0] term through blend[-1]).
//
// R14 = R13 with the compile fix: __builtin_nontemporal_store requires a
// true vector type -> store through f32x4 (ext_vector_type), not HIP float4.
// Theory unchanged: the constant ~32us across six structural variants is L2
// write-allocate churn -- 64MB of output stores allocating/evicting through
// the 32MB aggregate L2 serializes the store stream. Output is write-once-
// never-read: nt stores stream to MALL/HBM without L2 allocation.

#define T_ 16384
#define TWO_T 32768
#define NFR 67             // staged frames: p0-1 .. p0+65
#define XSTRIDE 72         // ushorts per frame row (144 B; benign banking)

typedef __bf16 bf16x8 __attribute__((ext_vector_type(8)));
typedef __bf16 bf16x4 __attribute__((ext_vector_type(4)));
typedef float  f32x4  __attribute__((ext_vector_type(4)));
typedef unsigned short u16x8 __attribute__((ext_vector_type(8)));

__device__ __forceinline__ float sigmoidf_(float z) {
    return 1.0f / (1.0f + expf(-z));
}

__device__ __forceinline__ unsigned short f2bf(float f) {
    union { float f; uint32_t u; } v; v.f = f;
    uint32_t u = v.u;
    return (unsigned short)((u + 0x7FFFu + ((u >> 16) & 1u)) >> 16);
}

// ---------------- prep: 64 blocks x 64 threads (proven, unchanged).
// Blocks 0..55: the 7 polyphase matrices as packed bf16 fragments:
//   frag (phase, ks, nt): lane l elem i = M[tap=ks>>1][c=(ks&1)*32+(l>>4)*8+i]
//                                          [f=nt*16+(l&15)]
// Blocks 56..63: b = fi-56; corr[b][{E,O}][f] = sum_c K[{1,0}][c][f]*(1-w_c)*x[b,0,c]
__global__ void lu_prep_kernel(const float* __restrict__ iw,
                               const float* __restrict__ ck,
                               const float* __restrict__ x,
                               unsigned short* __restrict__ bp,
                               float* __restrict__ corrf) {
    int fi = blockIdx.x;
    int l  = threadIdx.x;
    if (fi < 56) {
        int phase, ks, nt;
        if (fi < 24) { phase = 0; ks = fi >> 2; nt = fi & 3; }
        else         { phase = 1; ks = (fi - 24) >> 2; nt = (fi - 24) & 3; }
        int tap = ks >> 1;
        int n   = nt * 16 + (l & 15);
        int c0  = ((ks & 1) << 5) + ((l >> 4) << 3);
        u16x8 pk;
#pragma unroll
        for (int i = 0; i < 8; ++i) {
            int c = c0 + i;
            float w = sigmoidf_(iw[c]);
            float v;
            #define CK(k) ck[((k) * 64 + c) * 64 + n]
            if (phase == 0) {
                if (tap == 0)      v = CK(0) + w * CK(1);
                else if (tap == 1) v = (1.f - w) * CK(1) + CK(2) + w * CK(3);
                else               v = (1.f - w) * CK(3) + CK(4);
            } else {
                if (tap == 0)      v = w * CK(0);
                else if (tap == 1) v = (1.f - w) * CK(0) + CK(1) + w * CK(2);
                else if (tap == 2) v = (1.f - w) * CK(2) + CK(3) + w * CK(4);
                else               v = (1.f - w) * CK(4);
            }
            #undef CK
            pk[i] = f2bf(v);
        }
        *(u16x8*)(bp + (((size_t)fi * 64) + l) * 8) = pk;
    } else {
        int b = fi - 56;
        int f = l;
        float cE = 0.f, cO = 0.f;
#pragma unroll
        for (int c = 0; c < 64; ++c) {
            float w = sigmoidf_(iw[c]);
            float g = (1.f - w) * x[(size_t)b * T_ * 64 + c];
            cE += ck[(64 + c) * 64 + f] * g;   // K1
            cO += ck[c * 64 + f] * g;          // K0
        }
        corrf[b * 128 + f]      = cE;
        corrf[b * 128 + 64 + f] = cO;
    }
}

// ---------------- main ----------------
__global__ __launch_bounds__(256, 4) void lu_main_kernel(
        const float* __restrict__ x,
        const unsigned short* __restrict__ bp,
        const float* __restrict__ corrf,
        const float* __restrict__ bias,
        float* __restrict__ out) {
    __shared__ __align__(16) unsigned short xl[NFR * XSTRIDE];   // 9,648 B

    const int bid  = blockIdx.x;        // 0..2047
    const int b    = bid >> 8;
    const int q    = bid & 255;
    const int p0   = q << 6;            // 64 time-pairs per block
    const int tid  = threadIdx.x;
    const int lane = tid & 63;
    const int wv   = tid >> 6;          // wave = filter tile

    const float* xb = x + (size_t)b * T_ * 64;

    // ---- cooperative bf16 staging: 67 frames x 16 chunks = 1072 items ----
#pragma unroll
    for (int it = 0; it < 5; ++it) {
        int idx = it * 256 + tid;
        if (idx < NFR * 16) {
            int j  = idx >> 4;
            int c4 = (idx & 15) << 2;
            int gf = p0 - 1 + j;
            float4 v = make_float4(0.f, 0.f, 0.f, 0.f);
            if ((unsigned)gf < (unsigned)T_)
                v = *(const float4*)(xb + ((size_t)gf << 6) + c4);
            bf16x4 pk;
            pk[0] = (__bf16)v.x; pk[1] = (__bf16)v.y;
            pk[2] = (__bf16)v.z; pk[3] = (__bf16)v.w;
            *(bf16x4*)(xl + j * XSTRIDE + c4) = pk;
        }
    }

    // ---- weight A-fragments + bias (resident, loaded once) ----
    bf16x8 We[6], Wo[8];
#pragma unroll
    for (int ks = 0; ks < 6; ++ks)
        We[ks] = __builtin_bit_cast(bf16x8,
            *(const u16x8*)(bp + (((size_t)(ks * 4 + wv)) * 64 + lane) * 8));
#pragma unroll
    for (int ks = 0; ks < 8; ++ks)
        Wo[ks] = __builtin_bit_cast(bf16x8,
            *(const u16x8*)(bp + (((size_t)(24 + ks * 4 + wv)) * 64 + lane) * 8));

    const int hi  = lane >> 4;
    const int col = lane & 15;          // time-pair within window
    const float4 bias4 = *(const float4*)(bias + (wv << 4) + (hi << 2));

    __syncthreads();

#pragma unroll
    for (int w = 0; w < 4; ++w) {
        f32x4 accE = {0.f, 0.f, 0.f, 0.f};
        f32x4 accO = {0.f, 0.f, 0.f, 0.f};
#pragma unroll
        for (int tap = 0; tap < 4; ++tap) {
            int r = (w << 4) + col + tap;           // row 0..66
            bf16x8 x0 = __builtin_bit_cast(bf16x8,
                *(const u16x8*)(xl + r * XSTRIDE + (hi << 3)));
            bf16x8 x1 = __builtin_bit_cast(bf16x8,
                *(const u16x8*)(xl + r * XSTRIDE + 32 + (hi << 3)));
            if (tap < 3) {
                accE = __builtin_amdgcn_mfma_f32_16x16x32_bf16(We[tap * 2],     x0, accE, 0, 0, 0);
                accE = __builtin_amdgcn_mfma_f32_16x16x32_bf16(We[tap * 2 + 1], x1, accE, 0, 0, 0);
            }
            accO = __builtin_amdgcn_mfma_f32_16x16x32_bf16(Wo[tap * 2],     x0, accO, 0, 0, 0);
            accO = __builtin_amdgcn_mfma_f32_16x16x32_bf16(Wo[tap * 2 + 1], x1, accO, 0, 0, 0);
        }

        // ---- boundary correction (output frames 0,1 of each batch) ----
        if (((q | w) == 0) && col == 0) {
            const float4 cE4 = *(const float4*)(corrf + b * 128 + (wv << 4) + (hi << 2));
            const float4 cO4 = *(const float4*)(corrf + b * 128 + 64 + (wv << 4) + (hi << 2));
            accE[0] -= cE4.x; accE[1] -= cE4.y; accE[2] -= cE4.z; accE[3] -= cE4.w;
            accO[0] -= cO4.x; accO[1] -= cO4.y; accO[2] -= cO4.z; accO[3] -= cO4.w;
        }

        // ---- epilogue: bias + leaky_relu, NONTEMPORAL dwordx4 stores ----
        const int tl = p0 + (w << 4) + col;
        const size_t fbase = ((size_t)b * TWO_T + ((size_t)tl << 1)) * 64
                           + (wv << 4) + (hi << 2);
        f32x4 vE, vO;
        {
            float e0 = accE[0] + bias4.x, e1 = accE[1] + bias4.y,
                  e2 = accE[2] + bias4.z, e3 = accE[3] + bias4.w;
            vE[0] = e0 >= 0.f ? e0 : 0.3f * e0;
            vE[1] = e1 >= 0.f ? e1 : 0.3f * e1;
            vE[2] = e2 >= 0.f ? e2 : 0.3f * e2;
            vE[3] = e3 >= 0.f ? e3 : 0.3f * e3;
            float o0 = accO[0] + bias4.x, o1 = accO[1] + bias4.y,
                  o2 = accO[2] + bias4.z, o3 = accO[3] + bias4.w;
            vO[0] = o0 >= 0.f ? o0 : 0.3f * o0;
            vO[1] = o1 >= 0.f ? o1 : 0.3f * o1;
            vO[2] = o2 >= 0.f ? o2 : 0.3f * o2;
            vO[3] = o3 >= 0.f ? o3 : 0.3f * o3;
        }
        __builtin_nontemporal_store(vE, (f32x4*)(out + fbase));        // even
        __builtin_nontemporal_store(vO, (f32x4*)(out + fbase + 64));   // odd
    }
}

extern "C" void kernel_launch(void* const* d_in, const int* in_sizes, int n_in,
                              void* d_out, int out_size, void* d_ws, size_t ws_size,
                              hipStream_t stream) {
    (void)in_sizes; (void)n_in; (void)out_size; (void)ws_size;
    const float* x    = (const float*)d_in[0];
    const float* iw   = (const float*)d_in[1];
    const float* ck   = (const float*)d_in[2];
    const float* bias = (const float*)d_in[3];
    float* out = (float*)d_out;
    unsigned short* bp = (unsigned short*)d_ws;            // 57,344 B
    float* corrf = (float*)((char*)d_ws + 57344);          // 4,096 B

    lu_prep_kernel<<<64, 64, 0, stream>>>(iw, ck, x, bp, corrf);
    lu_main_kernel<<<2048, 256, 0, stream>>>(x, bp, corrf, bias, out);
}